// Round 2
// baseline (94.608 us; speedup 1.0000x reference)
//
#include <hip/hip_runtime.h>

// GlobalAttentionModule collapses algebraically:
//   weight = softmax(score, axis=-1)  =>  sum_j weight[b,c,i,j] == 1
//   out = (v[:,:,:,None] * weight).sum(-1) = v
// where v = relu(GroupNorm32(Wv @ feat + bv, gn_v_g, gn_v_b)).
// Only inputs 0 (feat), 5 (Wv), 6 (bv), 7 (gn_v_g), 8 (gn_v_b) matter.
// All tensors are float32 storage (bf16-quantized values), per the reference.

#define BATCH  2
#define CH     128
#define NPOS   512
#define GROUPS 32
#define CPG    4            // channels per group = 128/32
#define GEPS   1e-5f

// One block per (batch, group): 4 channels x 512 positions (= 2048 elements,
// exactly the GroupNorm reduction span). 256 threads; each thread owns
// positions n = 2t, 2t+1 for all 4 channels (8 fp32 values in registers).
__global__ __launch_bounds__(256) void vpath_kernel(
    const float* __restrict__ feat,   // [B, C, N]
    const float* __restrict__ Wv,     // [C, C]  (out_ch, in_ch)
    const float* __restrict__ bv,     // [C]
    const float* __restrict__ gam,    // [C]
    const float* __restrict__ bet,    // [C]
    float* __restrict__ out)          // [B, C, N]
{
    const int b   = blockIdx.x >> 5;
    const int g   = blockIdx.x & 31;
    const int ch0 = g * CPG;
    const int t   = threadIdx.x;      // 0..255

    __shared__ float w[CPG][CH];      // 2 KB: Wv rows for this group's channels
    __shared__ float red[8];          // per-wave partial sum / sumsq
    __shared__ float stats[2];        // mean, rsqrt(var+eps)

    // Stage Wv rows for channels ch0..ch0+3 into LDS (512 floats, 2/thread).
    {
        const int i0 = t * 2;
        #pragma unroll
        for (int k = 0; k < 2; ++k) {
            int i = i0 + k;
            int j = i >> 7;           // 0..3
            int c = i & 127;
            w[j][c] = Wv[(ch0 + j) * CH + c];
        }
    }
    __syncthreads();

    // v[b, ch0+j, 2t+e] = sum_c Wv[ch0+j, c] * feat[b, c, 2t+e]
    float acc0[CPG] = {0.f, 0.f, 0.f, 0.f};
    float acc1[CPG] = {0.f, 0.f, 0.f, 0.f};
    const float2* fp =
        reinterpret_cast<const float2*>(feat + (size_t)b * CH * NPOS) + t;
    #pragma unroll 4
    for (int c = 0; c < CH; ++c) {
        float2 f = fp[c * (NPOS / 2)];        // coalesced 8B/lane
        #pragma unroll
        for (int j = 0; j < CPG; ++j) {
            float wv = w[j][c];               // LDS broadcast (conflict-free)
            acc0[j] = fmaf(wv, f.x, acc0[j]);
            acc1[j] = fmaf(wv, f.y, acc1[j]);
        }
    }

    // Bias, then per-thread partial stats over the 8 held values.
    float s = 0.f, s2 = 0.f;
    #pragma unroll
    for (int j = 0; j < CPG; ++j) {
        float bias = bv[ch0 + j];
        acc0[j] += bias;
        acc1[j] += bias;
        s  += acc0[j] + acc1[j];
        s2 += acc0[j] * acc0[j] + acc1[j] * acc1[j];
    }

    // Wave (64-lane) shuffle reduction, then cross-wave via LDS.
    #pragma unroll
    for (int off = 32; off > 0; off >>= 1) {
        s  += __shfl_down(s, off);
        s2 += __shfl_down(s2, off);
    }
    const int wave = t >> 6;
    if ((t & 63) == 0) {
        red[wave]     = s;
        red[wave + 4] = s2;
    }
    __syncthreads();
    if (t == 0) {
        float S  = red[0] + red[1] + red[2] + red[3];
        float S2 = red[4] + red[5] + red[6] + red[7];
        const float inv_n = 1.0f / (float)(CPG * NPOS);   // 1/2048
        float m   = S * inv_n;
        float var = S2 * inv_n - m * m;
        stats[0] = m;
        stats[1] = rsqrtf(var + GEPS);
    }
    __syncthreads();
    const float m = stats[0];
    const float r = stats[1];

    // Normalize + affine + ReLU, store float2 (coalesced 8B/lane).
    float2* op =
        reinterpret_cast<float2*>(out + (size_t)(b * CH + ch0) * NPOS) + t;
    #pragma unroll
    for (int j = 0; j < CPG; ++j) {
        float ga = gam[ch0 + j];
        float be = bet[ch0 + j];
        float2 y;
        y.x = fmaxf((acc0[j] - m) * r * ga + be, 0.0f);
        y.y = fmaxf((acc1[j] - m) * r * ga + be, 0.0f);
        op[j * (NPOS / 2)] = y;
    }
}

extern "C" void kernel_launch(void* const* d_in, const int* in_sizes, int n_in,
                              void* d_out, int out_size, void* d_ws, size_t ws_size,
                              hipStream_t stream) {
    const float* feat = (const float*)d_in[0];   // [2,128,512]
    const float* Wv   = (const float*)d_in[5];   // [128,128]
    const float* bv   = (const float*)d_in[6];   // [128]
    const float* gng  = (const float*)d_in[7];   // [128]
    const float* gnb  = (const float*)d_in[8];   // [128]
    float* out = (float*)d_out;                  // [2,128,512]

    vpath_kernel<<<dim3(BATCH * GROUPS), dim3(256), 0, stream>>>(
        feat, Wv, bv, gng, gnb, out);
}